// Round 8
// baseline (304.923 us; speedup 1.0000x reference)
//
#include <hip/hip_runtime.h>
#include <hip/hip_bf16.h>
#include <math.h>

#define NN 20000
#define NE 320000
#define C0I 32
#define C1I 16
#define C0O 64
#define C1O 16
#define EPSF 1e-8f
#define STAGE_TOTAL 1671264   // total staged f32 elements
#define STAGE_V4    417816    // /4
#define RSTR 84               // LDS row stride (84 mod 32 = 20 -> 2-way max, free)

using bf16 = __hip_bfloat16;

__device__ __forceinline__ float bb2f(unsigned short u) {
    return __uint_as_float(((unsigned)u) << 16);
}

// wave-level LDS fence: drain outstanding ds ops + forbid compile-time motion
__device__ __forceinline__ void lds_fence() {
    asm volatile("s_waitcnt lgkmcnt(0)" ::: "memory");
    __builtin_amdgcn_sched_barrier(0);
}

// ---- kA: detect dtype + stage all float inputs as f32 (vectorized) + zero cnt ----
__global__ __launch_bounds__(256) void se3_convert(
    const void* s0, const void* s1, const void* s2, const void* s3,
    const void* s4, const void* s5, const void* s6, const void* s7,
    const void* s8, const void* s9, const void* s10, const void* s11,
    int* __restrict__ flag, float* __restrict__ dst, int* __restrict__ cnt) {
    __shared__ int sj;
    if (threadIdx.x == 0) sj = 0;
    __syncthreads();
    {   // f32 data read as bf16 at even indices shows junk exponents
        const unsigned short* p = (const unsigned short*)s0;
        bool junk = false;
        int i0 = threadIdx.x * 8;
#pragma unroll
        for (int k = 0; k < 4; ++k) {
            float v = bb2f(p[i0 + k * 2]);
            if (!(fabsf(v) < 1e3f)) junk = true;
        }
        if (junk) atomicOr(&sj, 1);
    }
    __syncthreads();
    int isf32 = sj;
    int gid = blockIdx.x * 256 + threadIdx.x;
    if (gid == 0) *flag = isf32;
    if (gid < NN) cnt[gid] = 0;
    if (gid >= STAGE_V4) return;

    const void* src; int off;  // vec4 units
    if      (gid < 160000) { src = s0;  off = gid; }
    else if (gid < 400000) { src = s1;  off = gid - 160000; }
    else if (gid < 415000) { src = s2;  off = gid - 400000; }
    else if (gid < 415512) { src = s3;  off = gid - 415000; }
    else if (gid < 416024) { src = s4;  off = gid - 415512; }
    else if (gid < 416280) { src = s5;  off = gid - 416024; }
    else if (gid < 416792) { src = s6;  off = gid - 416280; }
    else if (gid < 417048) { src = s7;  off = gid - 416792; }
    else if (gid < 417176) { src = s8;  off = gid - 417048; }
    else if (gid < 417240) { src = s9;  off = gid - 417176; }
    else if (gid < 417752) { src = s10; off = gid - 417240; }
    else                   { src = s11; off = gid - 417752; }

    float4 v;
    if (isf32) {
        v = ((const float4*)src)[off];
    } else {
        ushort4 u = ((const ushort4*)src)[off];
        v = make_float4(bb2f(u.x), bb2f(u.y), bb2f(u.z), bb2f(u.w));
    }
    ((float4*)dst)[gid] = v;
}

// ---- kB: histogram + wqkc[32][48] + concatenated epilogue matrices
//      M0cat[80][64] = [Wv00 | Wv10 | Wself0], M1cat[64][16] = [Wv11|Wv01|Wself1] ----
__global__ __launch_bounds__(256) void se3_hist(
    const int* __restrict__ ei, int* __restrict__ cnt,
    const float* __restrict__ wq0, const float* __restrict__ wk00,
    const float* __restrict__ wk10,
    const float* __restrict__ wv00, const float* __restrict__ wv10,
    const float* __restrict__ wv01, const float* __restrict__ wv11,
    const float* __restrict__ ws0, const float* __restrict__ ws1,
    float* __restrict__ wqkc, float* __restrict__ M0cat, float* __restrict__ M1cat) {
    int gid = blockIdx.x * 256 + threadIdx.x;
    if (gid < 1536) {
        int cp = gid / 48, c = gid % 48;
        float a = 0.f;
        if (c < 32) { for (int j = 0; j < C0O; ++j) a += wq0[cp*C0O+j] * wk00[c*C0O+j]; }
        else        { for (int j = 0; j < C0O; ++j) a += wq0[cp*C0O+j] * wk10[(c-32)*C0O+j]; }
        wqkc[gid] = a;
    } else if (gid < 1536 + 5120) {
        int i = gid - 1536;
        int r = i >> 6, j = i & 63;
        M0cat[i] = (r < 32) ? wv00[r*64+j] : (r < 48) ? wv10[(r-32)*64+j] : ws0[(r-48)*64+j];
    } else if (gid < 1536 + 5120 + 1024) {
        int i = gid - 6656;
        int r = i >> 4, f = i & 15;
        M1cat[i] = (r < 16) ? wv11[r*16+f] : (r < 48) ? wv01[(r-16)*16+f] : ws1[(r-48)*16+f];
    }
    if (gid < NE) atomicAdd(&cnt[ei[NE + gid]], 1);
}

// ---- kC: exclusive scan of cnt[NN] -> rowptr, wptr ----
__global__ __launch_bounds__(1024) void se3_scan(
    const int* __restrict__ cnt, int* __restrict__ rowptr, int* __restrict__ wptr) {
    __shared__ int tmp[1024];
    int t = threadIdx.x;
    int base = t * 20;
    int v[20]; int s = 0;
#pragma unroll
    for (int i = 0; i < 20; ++i) {
        int idx = base + i;
        int c = (idx < NN) ? cnt[idx] : 0;
        v[i] = s; s += c;
    }
    tmp[t] = s;
    __syncthreads();
    for (int off = 1; off < 1024; off <<= 1) {
        int x = (t >= off) ? tmp[t - off] : 0;
        __syncthreads();
        tmp[t] += x;
        __syncthreads();
    }
    int tb = (t > 0) ? tmp[t - 1] : 0;
#pragma unroll
    for (int i = 0; i < 20; ++i) {
        int idx = base + i;
        if (idx < NN) { int r = tb + v[i]; rowptr[idx] = r; wptr[idx] = r; }
    }
    if (t == 1023) rowptr[NN] = NE;
}

// ---- kD: scatter src node ids into dst-sorted CSR order ----
__global__ __launch_bounds__(256) void se3_scatter(
    const int* __restrict__ ei, int* __restrict__ wptr, int* __restrict__ csr_src) {
    int e = blockIdx.x * 256 + threadIdx.x;
    if (e >= NE) return;
    int d = ei[NE + e];
    int off = atomicAdd(&wptr[d], 1);
    csr_src[off] = ei[e];
}

// ---- kF: per-node attention, 1 wave/node, 4 waves/block.
//      q computed inline (wqkc from L1); 16-edge chunks staged to LDS
//      rows[e][RSTR] = [x0(32)|x1(48)]; Y/w in registers (shfl broadcast);
//      epilogue reads M0cat/M1cat straight from global (L1-resident),
//      scratch aliased onto rows (dead after edge loop, fence-protected). ----
__global__ __launch_bounds__(256, 5) void se3_fused(
    const float* __restrict__ x0, const float* __restrict__ x1,
    const float* __restrict__ pos, const float* __restrict__ wqkc,
    const int* __restrict__ rowptr, const int* __restrict__ csr_src,
    const float* __restrict__ M0cat, const float* __restrict__ M1cat,
    const int* __restrict__ flag, void* __restrict__ out) {
    __shared__ __align__(16) float rows[4][16][RSTR];
    __shared__ float sq[4][48];

    int tid = threadIdx.x;
    int wv = tid >> 6, lane = tid & 63;
    int n = blockIdx.x * 4 + wv;                 // grid 5000 -> exactly NN waves
    float (*R)[RSTR] = rows[wv];
    float* q = sq[wv];

    // ---- inline qvec: q[c] = sum_cp x0n[cp] * wqkc[cp][c] ----
    float x0v_n = (lane < 32) ? x0[(size_t)n * 32 + lane] : 0.f;
    {
        int li = (lane < 48) ? lane : 0;
        float qh = 0.f;
        for (int cp = 0; cp < 32; ++cp)
            qh += __shfl(x0v_n, cp) * wqkc[cp * 48 + li];
        if (lane < 48) q[lane] = qh;
    }
    float pnx = pos[n*3], pny = pos[n*3+1], pnz = pos[n*3+2];
    int p0 = rowptr[n], deg = rowptr[n+1] - p0;

    float m = -INFINITY, zz = 0.f;
    float aggA = 0.f, aggB = 0.f, Cx = 0.f, Cy = 0.f, Cz = 0.f;
    int e4 = lane >> 2, j4 = lane & 3;
    int cc = (lane >= 32 && lane < 48) ? (lane - 32) : 0;

    for (int base = 0; base < deg; base += 16) {
        int nch = min(16, deg - base);
        float Yx = 0.f, Yy = 0.f, Yz = 0.f;
        // ---- stage: 4 lanes per edge; Y computed by ALL 4 lanes into regs ----
        if (e4 < nch) {
            int s_e = csr_src[p0 + base + e4];
            float rx = pnx - pos[s_e*3], ry = pny - pos[s_e*3+1], rz = pnz - pos[s_e*3+2];
            float inv = 1.f / (sqrtf(rx*rx + ry*ry + rz*rz) + EPSF);
            Yx = rx*inv; Yy = ry*inv; Yz = rz*inv;
            const float4* px0 = (const float4*)(x0 + (size_t)s_e * 32);
            float4 a0 = px0[j4*2], a1 = px0[j4*2+1];
            *(float4*)&R[e4][j4*8]     = a0;
            *(float4*)&R[e4][j4*8+4]   = a1;
            const float4* px1 = (const float4*)(x1 + (size_t)s_e * 48);
            float4 b0 = px1[j4*3], b1 = px1[j4*3+1], b2 = px1[j4*3+2];
            *(float4*)&R[e4][32+j4*12]   = b0;
            *(float4*)&R[e4][32+j4*12+4] = b1;
            *(float4*)&R[e4][32+j4*12+8] = b2;
        }
        lds_fence();   // stage writes (and first-iter sq write) visible to wave
        // ---- logits: lane (e4,j4) covers features c = j4+4k; Y from own regs ----
        float part = 0.f;
        if (e4 < nch) {
#pragma unroll
            for (int k = 0; k < 12; ++k) {
                int c = j4 + 4*k;
                float kv;
                if (c < 32) kv = R[e4][c];
                else {
                    int c1 = c - 32;
                    kv = R[e4][32+3*c1]*Yx + R[e4][32+3*c1+1]*Yy + R[e4][32+3*c1+2]*Yz;
                }
                part += kv * q[c];
            }
        }
        part += __shfl_xor(part, 1);
        part += __shfl_xor(part, 2);
        float lg = (e4 < nch) ? part * 0.125f : -INFINITY;   // 1/sqrt(64)
        float mc = lg;
        mc = fmaxf(mc, __shfl_xor(mc, 4));
        mc = fmaxf(mc, __shfl_xor(mc, 8));
        mc = fmaxf(mc, __shfl_xor(mc, 16));
        mc = fmaxf(mc, __shfl_xor(mc, 32));
        float nm = fmaxf(m, mc);
        float f0 = __expf(m - nm);               // first chunk: exp(-inf)=0
        float w  = (e4 < nch) ? __expf(lg - nm) : 0.f;
        float sw = (j4 == 0) ? w : 0.f;
        sw += __shfl_xor(sw, 1);  sw += __shfl_xor(sw, 2);
        sw += __shfl_xor(sw, 4);  sw += __shfl_xor(sw, 8);
        sw += __shfl_xor(sw, 16); sw += __shfl_xor(sw, 32);
        zz = zz * f0 + sw;
        m = nm;
        aggA *= f0; aggB *= f0; Cx *= f0; Cy *= f0; Cz *= f0;
        // ---- Phase B: lane = feature; w/Y broadcast from lane 4e (registers) ----
#pragma unroll 4
        for (int e = 0; e < nch; ++e) {
            float we = __shfl(w, e * 4);
            float Y0 = __shfl(Yx, e * 4);
            float Y1 = __shfl(Yy, e * 4);
            float Y2 = __shfl(Yz, e * 4);
            float x1v = (lane < 48) ? R[e][32 + lane] : 0.f;
            if (lane < 32) {
                float wx = we * R[e][lane];
                aggA += wx;
                Cx += wx * Y0; Cy += wx * Y1; Cz += wx * Y2;
            } else if (lane < 48) {
                float xd = R[e][32+3*cc]*Y0 + R[e][32+3*cc+1]*Y1 + R[e][32+3*cc+2]*Y2;
                aggA += we * xd;
            }
            aggB += we * x1v;
        }
        lds_fence();   // Phase-B reads done before next chunk overwrites R
    }

    // ---- epilogue: scratch aliased onto rows[wv] (dead after edge loop) ----
    float invz = 1.f / (zz + EPSF);
    float* scw = (float*)rows[wv];
    // feat rows: [0-47] = [a0agg | dotagg], [48-79] = x0n
    // G rows (3r+d layout at 96+): [96-143] x1agg, [144-239] C, [240-287] x1n
    if (lane < 48) {
        scw[lane]       = aggA * invz;
        scw[96 + lane]  = aggB * invz;                 // x1agg, layout 3c+d
        scw[240 + lane] = x1[(size_t)n * 48 + lane];   // x1n
    }
    if (lane < 32) {
        scw[48 + lane] = x0v_n;                        // x0n (from register)
        scw[144 + lane * 3 + 0] = Cx * invz;
        scw[144 + lane * 3 + 1] = Cy * invz;
        scw[144 + lane * 3 + 2] = Cz * invz;
    }
    lds_fence();   // scratch writes visible before cross-lane reads
    int isf32 = *flag;
    float o0 = 0.f;
    for (int r = 0; r < 80; ++r) o0 += scw[r] * M0cat[r * 64 + lane];
    int f = lane / 3, d = lane - 3 * f;
    float o1 = 0.f;
    if (lane < 48) {
        for (int r = 0; r < 64; ++r) o1 += scw[96 + 3 * r + d] * M1cat[r * 16 + f];
    }

    if (isf32) {
        ((float*)out)[(size_t)n * 64 + lane] = o0;
        if (lane < 48) ((float*)out)[(size_t)NN * 64 + (size_t)n * 48 + lane] = o1;
    } else {
        ((bf16*)out)[(size_t)n * 64 + lane] = __float2bfloat16(o0);
        if (lane < 48) ((bf16*)out)[(size_t)NN * 64 + (size_t)n * 48 + lane] = __float2bfloat16(o1);
    }
}

extern "C" void kernel_launch(void* const* d_in, const int* in_sizes, int n_in,
                              void* d_out, int out_size, void* d_ws, size_t ws_size,
                              hipStream_t stream) {
    const int* ei = (const int*)d_in[3];

    int* flag  = (int*)d_ws;
    float* ws  = (float*)d_ws + 16;
    float* x0f  = ws;                 // 640000
    float* x1f  = x0f + 640000;       // 960000
    float* posf = x1f + 960000;       // 60000
    float* wq0    = posf + 60000;     // 2048
    float* wk00   = wq0 + 2048;       // 2048
    float* wk10   = wk00 + 2048;      // 1024
    float* wv00   = wk10 + 1024;      // 2048
    float* wv10   = wv00 + 2048;      // 1024
    float* wv01   = wv10 + 1024;      // 512
    float* wv11   = wv01 + 512;       // 256
    float* wself0 = wv11 + 256;       // 2048
    float* wself1 = wself0 + 2048;    // 256
    float* wqkc  = ws + STAGE_TOTAL;          // 1536
    float* M0cat = wqkc + 1536;               // 5120
    float* M1cat = M0cat + 5120;              // 1024
    int* cnt     = (int*)(M1cat + 1024);      // NN
    int* rowptr  = cnt + NN;                  // NN+1
    int* wptr    = rowptr + NN + 1;           // NN
    int* csr_src = wptr + NN;                 // NE   (total ~8.3 MB, well under proven)

    se3_convert<<<1633, 256, 0, stream>>>(d_in[0], d_in[1], d_in[2],
        d_in[4], d_in[5], d_in[6], d_in[7], d_in[8], d_in[9], d_in[10], d_in[11], d_in[12],
        flag, ws, cnt);
    se3_hist<<<1250, 256, 0, stream>>>(ei, cnt, wq0, wk00, wk10,
        wv00, wv10, wv01, wv11, wself0, wself1, wqkc, M0cat, M1cat);
    se3_scan<<<1, 1024, 0, stream>>>(cnt, rowptr, wptr);
    se3_scatter<<<1250, 256, 0, stream>>>(ei, wptr, csr_src);
    se3_fused<<<5000, 256, 0, stream>>>(x0f, x1f, posf, wqkc, rowptr, csr_src,
        M0cat, M1cat, flag, d_out);
}

// Round 9
// 210.098 us; speedup vs baseline: 1.4513x; 1.4513x over previous
//
#include <hip/hip_runtime.h>
#include <hip/hip_bf16.h>
#include <math.h>

#define NN 20000
#define NE 320000
#define C0I 32
#define C1I 16
#define C0O 64
#define C1O 16
#define EPSF 1e-8f
#define STAGE_TOTAL 1671264   // total staged f32 elements
#define STAGE_V4    417816    // /4
#define RSTR 84               // LDS row stride (84 mod 32 = 20 -> 2-way max, free)

using bf16 = __hip_bfloat16;

__device__ __forceinline__ float bb2f(unsigned short u) {
    return __uint_as_float(((unsigned)u) << 16);
}

// wave-level LDS fence: drain outstanding ds ops + forbid compile-time motion
__device__ __forceinline__ void lds_fence() {
    asm volatile("s_waitcnt lgkmcnt(0)" ::: "memory");
    __builtin_amdgcn_sched_barrier(0);
}

// ---- kA: detect dtype + stage all float inputs as f32 (vectorized) + zero cnt ----
__global__ __launch_bounds__(256) void se3_convert(
    const void* s0, const void* s1, const void* s2, const void* s3,
    const void* s4, const void* s5, const void* s6, const void* s7,
    const void* s8, const void* s9, const void* s10, const void* s11,
    int* __restrict__ flag, float* __restrict__ dst, int* __restrict__ cnt) {
    __shared__ int sj;
    if (threadIdx.x == 0) sj = 0;
    __syncthreads();
    {   // f32 data read as bf16 at even indices shows junk exponents
        const unsigned short* p = (const unsigned short*)s0;
        bool junk = false;
        int i0 = threadIdx.x * 8;
#pragma unroll
        for (int k = 0; k < 4; ++k) {
            float v = bb2f(p[i0 + k * 2]);
            if (!(fabsf(v) < 1e3f)) junk = true;
        }
        if (junk) atomicOr(&sj, 1);
    }
    __syncthreads();
    int isf32 = sj;
    int gid = blockIdx.x * 256 + threadIdx.x;
    if (gid == 0) *flag = isf32;
    if (gid < NN) cnt[gid] = 0;
    if (gid >= STAGE_V4) return;

    const void* src; int off;  // vec4 units
    if      (gid < 160000) { src = s0;  off = gid; }
    else if (gid < 400000) { src = s1;  off = gid - 160000; }
    else if (gid < 415000) { src = s2;  off = gid - 400000; }
    else if (gid < 415512) { src = s3;  off = gid - 415000; }
    else if (gid < 416024) { src = s4;  off = gid - 415512; }
    else if (gid < 416280) { src = s5;  off = gid - 416024; }
    else if (gid < 416792) { src = s6;  off = gid - 416280; }
    else if (gid < 417048) { src = s7;  off = gid - 416792; }
    else if (gid < 417176) { src = s8;  off = gid - 417048; }
    else if (gid < 417240) { src = s9;  off = gid - 417176; }
    else if (gid < 417752) { src = s10; off = gid - 417240; }
    else                   { src = s11; off = gid - 417752; }

    float4 v;
    if (isf32) {
        v = ((const float4*)src)[off];
    } else {
        ushort4 u = ((const ushort4*)src)[off];
        v = make_float4(bb2f(u.x), bb2f(u.y), bb2f(u.z), bb2f(u.w));
    }
    ((float4*)dst)[gid] = v;
}

// ---- kB: histogram + wqkc[32][48] + concatenated epilogue matrices
//      M0cat[80][64] = [Wv00 | Wv10 | Wself0], M1cat[64][16] = [Wv11|Wv01|Wself1] ----
__global__ __launch_bounds__(256) void se3_hist(
    const int* __restrict__ ei, int* __restrict__ cnt,
    const float* __restrict__ wq0, const float* __restrict__ wk00,
    const float* __restrict__ wk10,
    const float* __restrict__ wv00, const float* __restrict__ wv10,
    const float* __restrict__ wv01, const float* __restrict__ wv11,
    const float* __restrict__ ws0, const float* __restrict__ ws1,
    float* __restrict__ wqkc, float* __restrict__ M0cat, float* __restrict__ M1cat) {
    int gid = blockIdx.x * 256 + threadIdx.x;
    if (gid < 1536) {
        int cp = gid / 48, c = gid % 48;
        float a = 0.f;
        if (c < 32) { for (int j = 0; j < C0O; ++j) a += wq0[cp*C0O+j] * wk00[c*C0O+j]; }
        else        { for (int j = 0; j < C0O; ++j) a += wq0[cp*C0O+j] * wk10[(c-32)*C0O+j]; }
        wqkc[gid] = a;
    } else if (gid < 1536 + 5120) {
        int i = gid - 1536;
        int r = i >> 6, j = i & 63;
        M0cat[i] = (r < 32) ? wv00[r*64+j] : (r < 48) ? wv10[(r-32)*64+j] : ws0[(r-48)*64+j];
    } else if (gid < 1536 + 5120 + 1024) {
        int i = gid - 6656;
        int r = i >> 4, f = i & 15;
        M1cat[i] = (r < 16) ? wv11[r*16+f] : (r < 48) ? wv01[(r-16)*16+f] : ws1[(r-48)*16+f];
    }
    if (gid < NE) atomicAdd(&cnt[ei[NE + gid]], 1);
}

// ---- kC: exclusive scan of cnt[NN] -> rowptr, wptr ----
__global__ __launch_bounds__(1024) void se3_scan(
    const int* __restrict__ cnt, int* __restrict__ rowptr, int* __restrict__ wptr) {
    __shared__ int tmp[1024];
    int t = threadIdx.x;
    int base = t * 20;
    int v[20]; int s = 0;
#pragma unroll
    for (int i = 0; i < 20; ++i) {
        int idx = base + i;
        int c = (idx < NN) ? cnt[idx] : 0;
        v[i] = s; s += c;
    }
    tmp[t] = s;
    __syncthreads();
    for (int off = 1; off < 1024; off <<= 1) {
        int x = (t >= off) ? tmp[t - off] : 0;
        __syncthreads();
        tmp[t] += x;
        __syncthreads();
    }
    int tb = (t > 0) ? tmp[t - 1] : 0;
#pragma unroll
    for (int i = 0; i < 20; ++i) {
        int idx = base + i;
        if (idx < NN) { int r = tb + v[i]; rowptr[idx] = r; wptr[idx] = r; }
    }
    if (t == 1023) rowptr[NN] = NE;
}

// ---- kD: scatter src node ids into dst-sorted CSR order ----
__global__ __launch_bounds__(256) void se3_scatter(
    const int* __restrict__ ei, int* __restrict__ wptr, int* __restrict__ csr_src) {
    int e = blockIdx.x * 256 + threadIdx.x;
    if (e >= NE) return;
    int d = ei[NE + e];
    int off = atomicAdd(&wptr[d], 1);
    csr_src[off] = ei[e];
}

// ---- kF: per-node attention, 1 wave/node, 4 waves/block.
//      q computed inline (wqkc from L1); 16-edge chunks staged to LDS
//      rows[e][RSTR] = [x0(32)|x1(48)]; Y/w in registers (shfl broadcast);
//      epilogue reads M0cat/M1cat straight from global (L2-resident),
//      scratch aliased onto rows (dead after edge loop, fence-protected).
//      NOTE: plain launch_bounds — round 8's (256,5) cap forced VGPR 92->48
//      and spilled ~400MB of scratch traffic (WRITE_SIZE 8.7->402 MB). ----
__global__ __launch_bounds__(256) void se3_fused(
    const float* __restrict__ x0, const float* __restrict__ x1,
    const float* __restrict__ pos, const float* __restrict__ wqkc,
    const int* __restrict__ rowptr, const int* __restrict__ csr_src,
    const float* __restrict__ M0cat, const float* __restrict__ M1cat,
    const int* __restrict__ flag, void* __restrict__ out) {
    __shared__ __align__(16) float rows[4][16][RSTR];
    __shared__ float sq[4][48];

    int tid = threadIdx.x;
    int wv = tid >> 6, lane = tid & 63;
    int n = blockIdx.x * 4 + wv;                 // grid 5000 -> exactly NN waves
    float (*R)[RSTR] = rows[wv];
    float* q = sq[wv];

    // ---- inline qvec: q[c] = sum_cp x0n[cp] * wqkc[cp][c] ----
    float x0v_n = (lane < 32) ? x0[(size_t)n * 32 + lane] : 0.f;
    {
        int li = (lane < 48) ? lane : 0;
        float qh = 0.f;
        for (int cp = 0; cp < 32; ++cp)
            qh += __shfl(x0v_n, cp) * wqkc[cp * 48 + li];
        if (lane < 48) q[lane] = qh;
    }
    float pnx = pos[n*3], pny = pos[n*3+1], pnz = pos[n*3+2];
    int p0 = rowptr[n], deg = rowptr[n+1] - p0;

    float m = -INFINITY, zz = 0.f;
    float aggA = 0.f, aggB = 0.f, Cx = 0.f, Cy = 0.f, Cz = 0.f;
    int e4 = lane >> 2, j4 = lane & 3;
    int cc = (lane >= 32 && lane < 48) ? (lane - 32) : 0;

    for (int base = 0; base < deg; base += 16) {
        int nch = min(16, deg - base);
        float Yx = 0.f, Yy = 0.f, Yz = 0.f;
        // ---- stage: 4 lanes per edge; Y computed by ALL 4 lanes into regs ----
        if (e4 < nch) {
            int s_e = csr_src[p0 + base + e4];
            float rx = pnx - pos[s_e*3], ry = pny - pos[s_e*3+1], rz = pnz - pos[s_e*3+2];
            float inv = 1.f / (sqrtf(rx*rx + ry*ry + rz*rz) + EPSF);
            Yx = rx*inv; Yy = ry*inv; Yz = rz*inv;
            const float4* px0 = (const float4*)(x0 + (size_t)s_e * 32);
            float4 a0 = px0[j4*2], a1 = px0[j4*2+1];
            *(float4*)&R[e4][j4*8]     = a0;
            *(float4*)&R[e4][j4*8+4]   = a1;
            const float4* px1 = (const float4*)(x1 + (size_t)s_e * 48);
            float4 b0 = px1[j4*3], b1 = px1[j4*3+1], b2 = px1[j4*3+2];
            *(float4*)&R[e4][32+j4*12]   = b0;
            *(float4*)&R[e4][32+j4*12+4] = b1;
            *(float4*)&R[e4][32+j4*12+8] = b2;
        }
        lds_fence();   // stage writes (and first-iter sq write) visible to wave
        // ---- logits: lane (e4,j4) covers features c = j4+4k; Y from own regs ----
        float part = 0.f;
        if (e4 < nch) {
#pragma unroll
            for (int k = 0; k < 12; ++k) {
                int c = j4 + 4*k;
                float kv;
                if (c < 32) kv = R[e4][c];
                else {
                    int c1 = c - 32;
                    kv = R[e4][32+3*c1]*Yx + R[e4][32+3*c1+1]*Yy + R[e4][32+3*c1+2]*Yz;
                }
                part += kv * q[c];
            }
        }
        part += __shfl_xor(part, 1);
        part += __shfl_xor(part, 2);
        float lg = (e4 < nch) ? part * 0.125f : -INFINITY;   // 1/sqrt(64)
        float mc = lg;
        mc = fmaxf(mc, __shfl_xor(mc, 4));
        mc = fmaxf(mc, __shfl_xor(mc, 8));
        mc = fmaxf(mc, __shfl_xor(mc, 16));
        mc = fmaxf(mc, __shfl_xor(mc, 32));
        float nm = fmaxf(m, mc);
        float f0 = __expf(m - nm);               // first chunk: exp(-inf)=0
        float w  = (e4 < nch) ? __expf(lg - nm) : 0.f;
        float sw = (j4 == 0) ? w : 0.f;
        sw += __shfl_xor(sw, 1);  sw += __shfl_xor(sw, 2);
        sw += __shfl_xor(sw, 4);  sw += __shfl_xor(sw, 8);
        sw += __shfl_xor(sw, 16); sw += __shfl_xor(sw, 32);
        zz = zz * f0 + sw;
        m = nm;
        aggA *= f0; aggB *= f0; Cx *= f0; Cy *= f0; Cz *= f0;
        // ---- Phase B: lane = feature; w/Y broadcast from lane 4e (registers) ----
#pragma unroll 4
        for (int e = 0; e < nch; ++e) {
            float we = __shfl(w, e * 4);
            float Y0 = __shfl(Yx, e * 4);
            float Y1 = __shfl(Yy, e * 4);
            float Y2 = __shfl(Yz, e * 4);
            float x1v = (lane < 48) ? R[e][32 + lane] : 0.f;
            if (lane < 32) {
                float wx = we * R[e][lane];
                aggA += wx;
                Cx += wx * Y0; Cy += wx * Y1; Cz += wx * Y2;
            } else if (lane < 48) {
                float xd = R[e][32+3*cc]*Y0 + R[e][32+3*cc+1]*Y1 + R[e][32+3*cc+2]*Y2;
                aggA += we * xd;
            }
            aggB += we * x1v;
        }
        lds_fence();   // Phase-B reads done before next chunk overwrites R
    }

    // ---- epilogue: scratch aliased onto rows[wv] (dead after edge loop) ----
    float invz = 1.f / (zz + EPSF);
    float* scw = (float*)rows[wv];
    // feat rows: [0-47] = [a0agg | dotagg], [48-79] = x0n
    // G rows (3r+d layout at 96+): [96-143] x1agg, [144-239] C, [240-287] x1n
    if (lane < 48) {
        scw[lane]       = aggA * invz;
        scw[96 + lane]  = aggB * invz;                 // x1agg, layout 3c+d
        scw[240 + lane] = x1[(size_t)n * 48 + lane];   // x1n
    }
    if (lane < 32) {
        scw[48 + lane] = x0v_n;                        // x0n (from register)
        scw[144 + lane * 3 + 0] = Cx * invz;
        scw[144 + lane * 3 + 1] = Cy * invz;
        scw[144 + lane * 3 + 2] = Cz * invz;
    }
    lds_fence();   // scratch writes visible before cross-lane reads
    int isf32 = *flag;
    float o0 = 0.f;
    for (int r = 0; r < 80; ++r) o0 += scw[r] * M0cat[r * 64 + lane];
    int f = lane / 3, d = lane - 3 * f;
    float o1 = 0.f;
    if (lane < 48) {
        for (int r = 0; r < 64; ++r) o1 += scw[96 + 3 * r + d] * M1cat[r * 16 + f];
    }

    if (isf32) {
        ((float*)out)[(size_t)n * 64 + lane] = o0;
        if (lane < 48) ((float*)out)[(size_t)NN * 64 + (size_t)n * 48 + lane] = o1;
    } else {
        ((bf16*)out)[(size_t)n * 64 + lane] = __float2bfloat16(o0);
        if (lane < 48) ((bf16*)out)[(size_t)NN * 64 + (size_t)n * 48 + lane] = __float2bfloat16(o1);
    }
}

extern "C" void kernel_launch(void* const* d_in, const int* in_sizes, int n_in,
                              void* d_out, int out_size, void* d_ws, size_t ws_size,
                              hipStream_t stream) {
    const int* ei = (const int*)d_in[3];

    int* flag  = (int*)d_ws;
    float* ws  = (float*)d_ws + 16;
    float* x0f  = ws;                 // 640000
    float* x1f  = x0f + 640000;       // 960000
    float* posf = x1f + 960000;       // 60000
    float* wq0    = posf + 60000;     // 2048
    float* wk00   = wq0 + 2048;       // 2048
    float* wk10   = wk00 + 2048;      // 1024
    float* wv00   = wk10 + 1024;      // 2048
    float* wv10   = wv00 + 2048;      // 1024
    float* wv01   = wv10 + 1024;      // 512
    float* wv11   = wv01 + 512;       // 256
    float* wself0 = wv11 + 256;       // 2048
    float* wself1 = wself0 + 2048;    // 256
    float* wqkc  = ws + STAGE_TOTAL;          // 1536
    float* M0cat = wqkc + 1536;               // 5120
    float* M1cat = M0cat + 5120;              // 1024
    int* cnt     = (int*)(M1cat + 1024);      // NN
    int* rowptr  = cnt + NN;                  // NN+1
    int* wptr    = rowptr + NN + 1;           // NN
    int* csr_src = wptr + NN;                 // NE   (total ~8.3 MB, well under proven)

    se3_convert<<<1633, 256, 0, stream>>>(d_in[0], d_in[1], d_in[2],
        d_in[4], d_in[5], d_in[6], d_in[7], d_in[8], d_in[9], d_in[10], d_in[11], d_in[12],
        flag, ws, cnt);
    se3_hist<<<1250, 256, 0, stream>>>(ei, cnt, wq0, wk00, wk10,
        wv00, wv10, wv01, wv11, wself0, wself1, wqkc, M0cat, M1cat);
    se3_scan<<<1, 1024, 0, stream>>>(cnt, rowptr, wptr);
    se3_scatter<<<1250, 256, 0, stream>>>(ei, wptr, csr_src);
    se3_fused<<<5000, 256, 0, stream>>>(x0f, x1f, posf, wqkc, rowptr, csr_src,
        M0cat, M1cat, flag, d_out);
}

// Round 10
// 201.303 us; speedup vs baseline: 1.5147x; 1.0437x over previous
//
#include <hip/hip_runtime.h>
#include <hip/hip_bf16.h>
#include <math.h>

#define NN 20000
#define NE 320000
#define C0I 32
#define C1I 16
#define C0O 64
#define C1O 16
#define EPSF 1e-8f
#define STAGE_TOTAL 1671264   // total staged f32 elements
#define STAGE_V4    417816    // /4
#define RSTR 84               // LDS row stride (84 mod 32 = 20 -> 2-way max, free)

using bf16 = __hip_bfloat16;

__device__ __forceinline__ float bb2f(unsigned short u) {
    return __uint_as_float(((unsigned)u) << 16);
}

// wave-level LDS fence: drain outstanding ds ops + forbid compile-time motion
__device__ __forceinline__ void lds_fence() {
    asm volatile("s_waitcnt lgkmcnt(0)" ::: "memory");
    __builtin_amdgcn_sched_barrier(0);
}

// ---- kA: detect dtype + stage all float inputs as f32 (vectorized) + zero cnt ----
__global__ __launch_bounds__(256) void se3_convert(
    const void* s0, const void* s1, const void* s2, const void* s3,
    const void* s4, const void* s5, const void* s6, const void* s7,
    const void* s8, const void* s9, const void* s10, const void* s11,
    int* __restrict__ flag, float* __restrict__ dst, int* __restrict__ cnt) {
    __shared__ int sj;
    if (threadIdx.x == 0) sj = 0;
    __syncthreads();
    {   // f32 data read as bf16 at even indices shows junk exponents
        const unsigned short* p = (const unsigned short*)s0;
        bool junk = false;
        int i0 = threadIdx.x * 8;
#pragma unroll
        for (int k = 0; k < 4; ++k) {
            float v = bb2f(p[i0 + k * 2]);
            if (!(fabsf(v) < 1e3f)) junk = true;
        }
        if (junk) atomicOr(&sj, 1);
    }
    __syncthreads();
    int isf32 = sj;
    int gid = blockIdx.x * 256 + threadIdx.x;
    if (gid == 0) *flag = isf32;
    if (gid < NN) cnt[gid] = 0;
    if (gid >= STAGE_V4) return;

    const void* src; int off;  // vec4 units
    if      (gid < 160000) { src = s0;  off = gid; }
    else if (gid < 400000) { src = s1;  off = gid - 160000; }
    else if (gid < 415000) { src = s2;  off = gid - 400000; }
    else if (gid < 415512) { src = s3;  off = gid - 415000; }
    else if (gid < 416024) { src = s4;  off = gid - 415512; }
    else if (gid < 416280) { src = s5;  off = gid - 416024; }
    else if (gid < 416792) { src = s6;  off = gid - 416280; }
    else if (gid < 417048) { src = s7;  off = gid - 416792; }
    else if (gid < 417176) { src = s8;  off = gid - 417048; }
    else if (gid < 417240) { src = s9;  off = gid - 417176; }
    else if (gid < 417752) { src = s10; off = gid - 417240; }
    else                   { src = s11; off = gid - 417752; }

    float4 v;
    if (isf32) {
        v = ((const float4*)src)[off];
    } else {
        ushort4 u = ((const ushort4*)src)[off];
        v = make_float4(bb2f(u.x), bb2f(u.y), bb2f(u.z), bb2f(u.w));
    }
    ((float4*)dst)[gid] = v;
}

// ---- kB: histogram + wqkc[32][48] + concatenated epilogue matrices
//      M0cat[80][64] = [Wv00 | Wv10 | Wself0], M1cat[64][16] = [Wv11|Wv01|Wself1] ----
__global__ __launch_bounds__(256) void se3_hist(
    const int* __restrict__ ei, int* __restrict__ cnt,
    const float* __restrict__ wq0, const float* __restrict__ wk00,
    const float* __restrict__ wk10,
    const float* __restrict__ wv00, const float* __restrict__ wv10,
    const float* __restrict__ wv01, const float* __restrict__ wv11,
    const float* __restrict__ ws0, const float* __restrict__ ws1,
    float* __restrict__ wqkc, float* __restrict__ M0cat, float* __restrict__ M1cat) {
    int gid = blockIdx.x * 256 + threadIdx.x;
    if (gid < 1536) {
        int cp = gid / 48, c = gid % 48;
        float a = 0.f;
        if (c < 32) { for (int j = 0; j < C0O; ++j) a += wq0[cp*C0O+j] * wk00[c*C0O+j]; }
        else        { for (int j = 0; j < C0O; ++j) a += wq0[cp*C0O+j] * wk10[(c-32)*C0O+j]; }
        wqkc[gid] = a;
    } else if (gid < 1536 + 5120) {
        int i = gid - 1536;
        int r = i >> 6, j = i & 63;
        M0cat[i] = (r < 32) ? wv00[r*64+j] : (r < 48) ? wv10[(r-32)*64+j] : ws0[(r-48)*64+j];
    } else if (gid < 1536 + 5120 + 1024) {
        int i = gid - 6656;
        int r = i >> 4, f = i & 15;
        M1cat[i] = (r < 16) ? wv11[r*16+f] : (r < 48) ? wv01[(r-16)*16+f] : ws1[(r-48)*16+f];
    }
    if (gid < NE) atomicAdd(&cnt[ei[NE + gid]], 1);
}

// ---- kC: exclusive scan of cnt[NN] -> rowptr, wptr ----
__global__ __launch_bounds__(1024) void se3_scan(
    const int* __restrict__ cnt, int* __restrict__ rowptr, int* __restrict__ wptr) {
    __shared__ int tmp[1024];
    int t = threadIdx.x;
    int base = t * 20;
    int v[20]; int s = 0;
#pragma unroll
    for (int i = 0; i < 20; ++i) {
        int idx = base + i;
        int c = (idx < NN) ? cnt[idx] : 0;
        v[i] = s; s += c;
    }
    tmp[t] = s;
    __syncthreads();
    for (int off = 1; off < 1024; off <<= 1) {
        int x = (t >= off) ? tmp[t - off] : 0;
        __syncthreads();
        tmp[t] += x;
        __syncthreads();
    }
    int tb = (t > 0) ? tmp[t - 1] : 0;
#pragma unroll
    for (int i = 0; i < 20; ++i) {
        int idx = base + i;
        if (idx < NN) { int r = tb + v[i]; rowptr[idx] = r; wptr[idx] = r; }
    }
    if (t == 1023) rowptr[NN] = NE;
}

// ---- kD: scatter src node ids into dst-sorted CSR order ----
__global__ __launch_bounds__(256) void se3_scatter(
    const int* __restrict__ ei, int* __restrict__ wptr, int* __restrict__ csr_src) {
    int e = blockIdx.x * 256 + threadIdx.x;
    if (e >= NE) return;
    int d = ei[NE + e];
    int off = atomicAdd(&wptr[d], 1);
    csr_src[off] = ei[e];
}

// ---- kF: per-node attention, 1 node = 1 wave = 1 BLOCK (64 threads).
//      Eliminates intra-block straggling (round 9: 4 nodes/block retired at the
//      slowest node's pace -> avg occupancy ~6 waves/CU) and lets the CU
//      scheduler backfill at single-wave granularity.
//      q computed inline (wqkc L1); 16-edge chunks staged to LDS
//      rows[e][RSTR] = [x0(32)|x1(48)]; Y/w in registers (shfl broadcast);
//      epilogue reads M0cat/M1cat from global (L1-resident after 1st block),
//      scratch aliased onto rows (dead after edge loop, fence-protected). ----
__global__ __launch_bounds__(64) void se3_fused(
    const float* __restrict__ x0, const float* __restrict__ x1,
    const float* __restrict__ pos, const float* __restrict__ wqkc,
    const int* __restrict__ rowptr, const int* __restrict__ csr_src,
    const float* __restrict__ M0cat, const float* __restrict__ M1cat,
    const int* __restrict__ flag, void* __restrict__ out) {
    __shared__ __align__(16) float rows[16][RSTR];
    __shared__ float sq[48];

    int lane = threadIdx.x;
    int n = blockIdx.x;                          // grid = NN blocks
    float (*R)[RSTR] = rows;
    float* q = sq;

    // ---- inline qvec: q[c] = sum_cp x0n[cp] * wqkc[cp][c] ----
    float x0v_n = (lane < 32) ? x0[(size_t)n * 32 + lane] : 0.f;
    {
        int li = (lane < 48) ? lane : 0;
        float qh = 0.f;
        for (int cp = 0; cp < 32; ++cp)
            qh += __shfl(x0v_n, cp) * wqkc[cp * 48 + li];
        if (lane < 48) q[lane] = qh;
    }
    float pnx = pos[n*3], pny = pos[n*3+1], pnz = pos[n*3+2];
    int p0 = rowptr[n], deg = rowptr[n+1] - p0;

    float m = -INFINITY, zz = 0.f;
    float aggA = 0.f, aggB = 0.f, Cx = 0.f, Cy = 0.f, Cz = 0.f;
    int e4 = lane >> 2, j4 = lane & 3;
    int cc = (lane >= 32 && lane < 48) ? (lane - 32) : 0;

    for (int base = 0; base < deg; base += 16) {
        int nch = min(16, deg - base);
        float Yx = 0.f, Yy = 0.f, Yz = 0.f;
        // ---- stage: 4 lanes per edge; Y computed by ALL 4 lanes into regs ----
        if (e4 < nch) {
            int s_e = csr_src[p0 + base + e4];
            float rx = pnx - pos[s_e*3], ry = pny - pos[s_e*3+1], rz = pnz - pos[s_e*3+2];
            float inv = 1.f / (sqrtf(rx*rx + ry*ry + rz*rz) + EPSF);
            Yx = rx*inv; Yy = ry*inv; Yz = rz*inv;
            const float4* px0 = (const float4*)(x0 + (size_t)s_e * 32);
            float4 a0 = px0[j4*2], a1 = px0[j4*2+1];
            *(float4*)&R[e4][j4*8]     = a0;
            *(float4*)&R[e4][j4*8+4]   = a1;
            const float4* px1 = (const float4*)(x1 + (size_t)s_e * 48);
            float4 b0 = px1[j4*3], b1 = px1[j4*3+1], b2 = px1[j4*3+2];
            *(float4*)&R[e4][32+j4*12]   = b0;
            *(float4*)&R[e4][32+j4*12+4] = b1;
            *(float4*)&R[e4][32+j4*12+8] = b2;
        }
        lds_fence();   // stage writes (and first-iter sq write) visible to wave
        // ---- logits: lane (e4,j4) covers features c = j4+4k; Y from own regs ----
        float part = 0.f;
        if (e4 < nch) {
#pragma unroll
            for (int k = 0; k < 12; ++k) {
                int c = j4 + 4*k;
                float kv;
                if (c < 32) kv = R[e4][c];
                else {
                    int c1 = c - 32;
                    kv = R[e4][32+3*c1]*Yx + R[e4][32+3*c1+1]*Yy + R[e4][32+3*c1+2]*Yz;
                }
                part += kv * q[c];
            }
        }
        part += __shfl_xor(part, 1);
        part += __shfl_xor(part, 2);
        float lg = (e4 < nch) ? part * 0.125f : -INFINITY;   // 1/sqrt(64)
        float mc = lg;
        mc = fmaxf(mc, __shfl_xor(mc, 4));
        mc = fmaxf(mc, __shfl_xor(mc, 8));
        mc = fmaxf(mc, __shfl_xor(mc, 16));
        mc = fmaxf(mc, __shfl_xor(mc, 32));
        float nm = fmaxf(m, mc);
        float f0 = __expf(m - nm);               // first chunk: exp(-inf)=0
        float w  = (e4 < nch) ? __expf(lg - nm) : 0.f;
        float sw = (j4 == 0) ? w : 0.f;
        sw += __shfl_xor(sw, 1);  sw += __shfl_xor(sw, 2);
        sw += __shfl_xor(sw, 4);  sw += __shfl_xor(sw, 8);
        sw += __shfl_xor(sw, 16); sw += __shfl_xor(sw, 32);
        zz = zz * f0 + sw;
        m = nm;
        aggA *= f0; aggB *= f0; Cx *= f0; Cy *= f0; Cz *= f0;
        // ---- Phase B: lane = feature; w/Y broadcast from lane 4e (registers) ----
#pragma unroll 4
        for (int e = 0; e < nch; ++e) {
            float we = __shfl(w, e * 4);
            float Y0 = __shfl(Yx, e * 4);
            float Y1 = __shfl(Yy, e * 4);
            float Y2 = __shfl(Yz, e * 4);
            float x1v = (lane < 48) ? R[e][32 + lane] : 0.f;
            if (lane < 32) {
                float wx = we * R[e][lane];
                aggA += wx;
                Cx += wx * Y0; Cy += wx * Y1; Cz += wx * Y2;
            } else if (lane < 48) {
                float xd = R[e][32+3*cc]*Y0 + R[e][32+3*cc+1]*Y1 + R[e][32+3*cc+2]*Y2;
                aggA += we * xd;
            }
            aggB += we * x1v;
        }
        lds_fence();   // Phase-B reads done before next chunk overwrites R
    }

    // ---- epilogue: scratch aliased onto rows (dead after edge loop) ----
    float invz = 1.f / (zz + EPSF);
    float* scw = (float*)rows;
    // feat rows: [0-47] = [a0agg | dotagg], [48-79] = x0n
    // G rows (3r+d layout at 96+): [96-143] x1agg, [144-239] C, [240-287] x1n
    if (lane < 48) {
        scw[lane]       = aggA * invz;
        scw[96 + lane]  = aggB * invz;                 // x1agg, layout 3c+d
        scw[240 + lane] = x1[(size_t)n * 48 + lane];   // x1n
    }
    if (lane < 32) {
        scw[48 + lane] = x0v_n;                        // x0n (from register)
        scw[144 + lane * 3 + 0] = Cx * invz;
        scw[144 + lane * 3 + 1] = Cy * invz;
        scw[144 + lane * 3 + 2] = Cz * invz;
    }
    lds_fence();   // scratch writes visible before cross-lane reads
    int isf32 = *flag;
    float o0 = 0.f;
    for (int r = 0; r < 80; ++r) o0 += scw[r] * M0cat[r * 64 + lane];
    int f = lane / 3, d = lane - 3 * f;
    float o1 = 0.f;
    if (lane < 48) {
        for (int r = 0; r < 64; ++r) o1 += scw[96 + 3 * r + d] * M1cat[r * 16 + f];
    }

    if (isf32) {
        ((float*)out)[(size_t)n * 64 + lane] = o0;
        if (lane < 48) ((float*)out)[(size_t)NN * 64 + (size_t)n * 48 + lane] = o1;
    } else {
        ((bf16*)out)[(size_t)n * 64 + lane] = __float2bfloat16(o0);
        if (lane < 48) ((bf16*)out)[(size_t)NN * 64 + (size_t)n * 48 + lane] = __float2bfloat16(o1);
    }
}

extern "C" void kernel_launch(void* const* d_in, const int* in_sizes, int n_in,
                              void* d_out, int out_size, void* d_ws, size_t ws_size,
                              hipStream_t stream) {
    const int* ei = (const int*)d_in[3];

    int* flag  = (int*)d_ws;
    float* ws  = (float*)d_ws + 16;
    float* x0f  = ws;                 // 640000
    float* x1f  = x0f + 640000;       // 960000
    float* posf = x1f + 960000;       // 60000
    float* wq0    = posf + 60000;     // 2048
    float* wk00   = wq0 + 2048;       // 2048
    float* wk10   = wk00 + 2048;      // 1024
    float* wv00   = wk10 + 1024;      // 2048
    float* wv10   = wv00 + 2048;      // 1024
    float* wv01   = wv10 + 1024;      // 512
    float* wv11   = wv01 + 512;       // 256
    float* wself0 = wv11 + 256;       // 2048
    float* wself1 = wself0 + 2048;    // 256
    float* wqkc  = ws + STAGE_TOTAL;          // 1536
    float* M0cat = wqkc + 1536;               // 5120
    float* M1cat = M0cat + 5120;              // 1024
    int* cnt     = (int*)(M1cat + 1024);      // NN
    int* rowptr  = cnt + NN;                  // NN+1
    int* wptr    = rowptr + NN + 1;           // NN
    int* csr_src = wptr + NN;                 // NE   (total ~8.3 MB, well under proven)

    se3_convert<<<1633, 256, 0, stream>>>(d_in[0], d_in[1], d_in[2],
        d_in[4], d_in[5], d_in[6], d_in[7], d_in[8], d_in[9], d_in[10], d_in[11], d_in[12],
        flag, ws, cnt);
    se3_hist<<<1250, 256, 0, stream>>>(ei, cnt, wq0, wk00, wk10,
        wv00, wv10, wv01, wv11, wself0, wself1, wqkc, M0cat, M1cat);
    se3_scan<<<1, 1024, 0, stream>>>(cnt, rowptr, wptr);
    se3_scatter<<<1250, 256, 0, stream>>>(ei, wptr, csr_src);
    se3_fused<<<NN, 64, 0, stream>>>(x0f, x1f, posf, wqkc, rowptr, csr_src,
        M0cat, M1cat, flag, d_out);
}